// Round 4
// baseline (248.114 us; speedup 1.0000x reference)
//
#include <hip/hip_runtime.h>

#define TT 256
#define BB 8192
#define DD 16
#define HH 8

__device__ __forceinline__ float fast_rcp(float v) { return __builtin_amdgcn_rcpf(v); }

// pull from lane^4 (partner part, bit0) : BitMode offset = (xor<<10)|(or<<5)|and
__device__ __forceinline__ float swz_xor4(float v) {
    return __int_as_float(__builtin_amdgcn_ds_swizzle(__float_as_int(v), 0x101F));
}
// pull from lane^8 (partner part, bit1)
__device__ __forceinline__ float swz_xor8(float v) {
    return __int_as_float(__builtin_amdgcn_ds_swizzle(__float_as_int(v), 0x201F));
}
// quad broadcast via DPP: every lane of the quad reads lane (quadbase + g)
#define QBCAST(x, g) __int_as_float(__builtin_amdgcn_mov_dpp(__float_as_int(x), (g)*0x55, 0xF, 0xF, true))

__global__ __launch_bounds__(256, 2)
void qlstm_fused_kernel(const float* __restrict__ inp,
                        const float* __restrict__ Wf, const float* __restrict__ bfv,
                        const float* __restrict__ Wi, const float* __restrict__ biv,
                        const float* __restrict__ Wu, const float* __restrict__ buv,
                        const float* __restrict__ Wo, const float* __restrict__ bov,
                        const float* __restrict__ pf, const float* __restrict__ pi,
                        const float* __restrict__ pu, const float* __restrict__ po,
                        float* __restrict__ out)
{
    const int tid  = blockIdx.x * blockDim.x + threadIdx.x;
    const int gate = tid & 3;          // 0=f, 1=i, 2=u(g), 3=o  (quad lanes)
    const int part = (tid >> 2) & 3;   // owns matvec rows / wires 2*part, 2*part+1
    const int b    = tid >> 4;         // sample

    const float* Wg = (gate == 0) ? Wf  : (gate == 1) ? Wi  : (gate == 2) ? Wu  : Wo;
    const float* bg = (gate == 0) ? bfv : (gate == 1) ? biv : (gate == 2) ? buv : bov;
    const float* pp = (gate == 0) ? pf  : (gate == 1) ? pi  : (gate == 2) ? pu  : po;

    // ---- own 2 weight rows (48 floats) + biases in VGPRs ----
    const int r0 = 2 * part;
    float w0[24], w1[24];
    {
        const float* p0 = Wg + r0 * 24;
        const float* p1 = Wg + (r0 + 1) * 24;
        #pragma unroll
        for (int k = 0; k < 6; ++k) {
            float4 v0 = *(const float4*)(p0 + 4 * k);
            float4 v1 = *(const float4*)(p1 + 4 * k);
            w0[4*k+0] = v0.x; w0[4*k+1] = v0.y; w0[4*k+2] = v0.z; w0[4*k+3] = v0.w;
            w1[4*k+0] = v1.x; w1[4*k+1] = v1.y; w1[4*k+2] = v1.z; w1[4*k+3] = v1.w;
        }
    }
    const float bs0 = bg[r0], bs1 = bg[r0 + 1];

    // ---- trig constants for all 8 wires ----
    float s1[HH], c1[HH], g2[HH], hn[HH];
    #pragma unroll
    for (int w = 0; w < HH; ++w) {
        float s, c;
        __sincosf(pp[w], &s, &c);
        s1[w] = s; c1[w] = c;
        __sincosf(pp[HH + w], &s, &c);
        g2[w] = c; hn[w] = -s;
    }

    // gate nonlinearity constants: sigmoid for f/i/o; tanh(v) = 2*sig(2v)-1 for u
    const float kPre  = (gate == 2) ? -2.0f : -1.0f;
    const float kPost = (gate == 2) ?  2.0f :  1.0f;
    const float kAdd  = (gate == 2) ? -1.0f :  0.0f;

    const bool pl = (part & 1) != 0;   // position within xor4 pair
    const bool hi = (part & 2) != 0;   // which 4-wire group we own

    float hw[HH];
    #pragma unroll
    for (int j = 0; j < HH; ++j) hw[j] = 0.f;
    float cs0 = 0.f, cs1 = 0.f;
    float h0 = 0.f, h1 = 0.f;

    const float* xp = inp + (size_t)b * DD;
    float* op = out + (size_t)b * HH + 2 * part + gate;   // used by gate<2 lanes

    // prefetch x_0
    float4 px0 = *(const float4*)(xp + 0);
    float4 px1 = *(const float4*)(xp + 4);
    float4 px2 = *(const float4*)(xp + 8);
    float4 px3 = *(const float4*)(xp + 12);

    #pragma unroll 1
    for (int t = 0; t < TT; ++t) {
        float xv[DD];
        xv[0]=px0.x; xv[1]=px0.y; xv[2]=px0.z; xv[3]=px0.w;
        xv[4]=px1.x; xv[5]=px1.y; xv[6]=px1.z; xv[7]=px1.w;
        xv[8]=px2.x; xv[9]=px2.y; xv[10]=px2.z; xv[11]=px2.w;
        xv[12]=px3.x; xv[13]=px3.y; xv[14]=px3.z; xv[15]=px3.w;

        // prefetch next x early
        const float* xn = xp + ((t < TT - 1) ? (size_t)BB * DD : 0);
        px0 = *(const float4*)(xn + 0);
        px1 = *(const float4*)(xn + 4);
        px2 = *(const float4*)(xn + 8);
        px3 = *(const float4*)(xn + 12);
        xp = xn;

        // ---- angles for own 2 rows (weights in regs) ----
        float a0 = bs0, a1 = bs1;
        #pragma unroll
        for (int d = 0; d < DD; ++d) { a0 = fmaf(w0[d], xv[d], a0); a1 = fmaf(w1[d], xv[d], a1); }
        #pragma unroll
        for (int j = 0; j < HH; ++j) { a0 = fmaf(w0[DD + j], hw[j], a0); a1 = fmaf(w1[DD + j], hw[j], a1); }

        // ---- butterfly: assemble all 8 angles on every lane ----
        float aw[HH];
        {
            float o0 = swz_xor4(a0), o1 = swz_xor4(a1);
            float q0 = pl ? o0 : a0, q1 = pl ? o1 : a1;
            float q2 = pl ? a0 : o0, q3 = pl ? a1 : o1;
            float r0_ = swz_xor8(q0), r1_ = swz_xor8(q1);
            float r2_ = swz_xor8(q2), r3_ = swz_xor8(q3);
            aw[0] = hi ? r0_ : q0;  aw[1] = hi ? r1_ : q1;
            aw[2] = hi ? r2_ : q2;  aw[3] = hi ? r3_ : q3;
            aw[4] = hi ? q0 : r0_;  aw[5] = hi ? q1 : r1_;
            aw[6] = hi ? q2 : r2_;  aw[7] = hi ? q3 : r3_;
        }

        // ---- Bloch vectors (x,z scaled cos; sy = +sin = -by) ----
        float bxv[HH], syv[HH], bzv[HH];
        #pragma unroll
        for (int w = 0; w < HH; ++w) {
            float sa, ca;
            __sincosf(aw[w], &sa, &ca);
            bxv[w] = s1[w] * ca;
            bzv[w] = c1[w] * ca;
            syv[w] = sa;
        }

        // ---- bond-2 transfer recursion -> E[8] ----
        // (w=0 special case from f=(1,0,0,1); note ny = -hn*by*fz = +hn*sy)
        float E[HH];
        float f0 = g2[0] * bzv[0];
        float fx = hn[0] * bxv[0];
        float fy = hn[0] * syv[0];
        float fz = g2[0];
        E[0] = fmaf(bxv[1], fx, f0);
        #pragma unroll
        for (int w = 1; w < HH - 1; ++w) {
            float n0 = g2[w] * fmaf(bzv[w], fz, -(syv[w] * fy));
            float nx = hn[w] * fmaf(bxv[w], f0, fx);
            float ny = hn[w] * fmaf(syv[w], fz, bzv[w] * fy);
            float nz = g2[w] * fmaf(bxv[w], fx, f0);
            f0 = n0; fx = nx; fy = ny; fz = nz;
            E[w] = fmaf(bxv[w + 1], fx, f0);
        }
        {
            float n0 = g2[7] * fmaf(bzv[7], fz, -(syv[7] * fy));
            float nx = hn[7] * fmaf(bxv[7], f0, fx);
            E[7] = n0 + nx;
        }

        // ---- own 2 E values (select tree; indices wave-varying) ----
        float u0 = hi ? E[4] : E[0], u1 = hi ? E[5] : E[1];
        float u2 = hi ? E[6] : E[2], u3 = hi ? E[7] : E[3];
        float e0 = pl ? u2 : u0;
        float e1 = pl ? u3 : u1;

        // ---- gate nonlinearity (own 2 j's) ----
        float G0 = fmaf(kPost, fast_rcp(1.0f + __expf(kPre * e0)), kAdd);
        float G1 = fmaf(kPost, fast_rcp(1.0f + __expf(kPre * e1)), kAdd);

        // ---- quad (gate) exchange + LSTM pointwise ----
        {
            float fj = QBCAST(G0, 0), ij = QBCAST(G0, 1), uj = QBCAST(G0, 2), oj = QBCAST(G0, 3);
            cs0 = fmaf(fj, cs0, ij * uj);
            float th = fmaf(2.0f, fast_rcp(1.0f + __expf(-2.0f * cs0)), -1.0f);
            h0 = oj * th;
        }
        {
            float fj = QBCAST(G1, 0), ij = QBCAST(G1, 1), uj = QBCAST(G1, 2), oj = QBCAST(G1, 3);
            cs1 = fmaf(fj, cs1, ij * uj);
            float th = fmaf(2.0f, fast_rcp(1.0f + __expf(-2.0f * cs1)), -1.0f);
            h1 = oj * th;
        }

        // ---- butterfly h back to full hw[8] ----
        {
            float o0 = swz_xor4(h0), o1 = swz_xor4(h1);
            float q0 = pl ? o0 : h0, q1 = pl ? o1 : h1;
            float q2 = pl ? h0 : o0, q3 = pl ? h1 : o1;
            float r0_ = swz_xor8(q0), r1_ = swz_xor8(q1);
            float r2_ = swz_xor8(q2), r3_ = swz_xor8(q3);
            hw[0] = hi ? r0_ : q0;  hw[1] = hi ? r1_ : q1;
            hw[2] = hi ? r2_ : q2;  hw[3] = hi ? r3_ : q3;
            hw[4] = hi ? q0 : r0_;  hw[5] = hi ? q1 : r1_;
            hw[6] = hi ? q2 : r2_;  hw[7] = hi ? q3 : r3_;
        }

        // ---- store h_t: gate 0 stores j=2p, gate 1 stores j=2p+1 ----
        if (gate < 2) *op = gate ? h1 : h0;
        op += (size_t)BB * HH;
    }

    // ---- final hx, cx ----
    if (gate < 2) {
        const size_t hx_off = (size_t)TT * BB * HH;
        out[hx_off + (size_t)b * HH + 2 * part + gate] = gate ? h1 : h0;
        out[hx_off + (size_t)BB * HH + (size_t)b * HH + 2 * part + gate] = gate ? cs1 : cs0;
    }
}

extern "C" void kernel_launch(void* const* d_in, const int* in_sizes, int n_in,
                              void* d_out, int out_size, void* d_ws, size_t ws_size,
                              hipStream_t stream) {
    (void)in_sizes; (void)n_in; (void)d_ws; (void)ws_size; (void)out_size;
    const float* inp = (const float*)d_in[0];
    const float* Wf  = (const float*)d_in[1];
    const float* bf  = (const float*)d_in[2];
    const float* Wi  = (const float*)d_in[3];
    const float* bi  = (const float*)d_in[4];
    const float* Wu  = (const float*)d_in[5];
    const float* bu  = (const float*)d_in[6];
    const float* Wo  = (const float*)d_in[7];
    const float* bo  = (const float*)d_in[8];
    const float* pf  = (const float*)d_in[9];
    const float* pi  = (const float*)d_in[10];
    const float* pu  = (const float*)d_in[11];
    const float* po  = (const float*)d_in[12];
    float* out = (float*)d_out;

    const int threads = BB * 16;   // 16 lanes (4 gates x 4 parts) per sample
    dim3 block(256);
    dim3 grid(threads / 256);
    qlstm_fused_kernel<<<grid, block, 0, stream>>>(inp, Wf, bf, Wi, bi, Wu, bu,
                                                   Wo, bo, pf, pi, pu, po, out);
}